// Round 6
// baseline (14788.683 us; speedup 1.0000x reference)
//
#include <hip/hip_runtime.h>
#include <hip/hip_cooperative_groups.h>

namespace cg = cooperative_groups;

constexpr int N    = 4096;
constexpr int T    = 2048;
constexpr int NBLK = 256;                 // one WG per CU
constexpr int NTHR = 1024;                // 16 waves
constexpr int ROWS_PER_WG = N / NBLK;     // 16 -> 1 row per wave

struct Params {
    const float *x_in, *w, *E_L, *C_m, *G, *R_I, *f_v, *f_I, *dts, *b_s,
                *a_v, *b_v, *tinf, *dV, *I_A, *v0, *ts0, *tv0, *ia0;
    float *out;                   // [2, T, N]
    unsigned long long *ia_tag;   // 2 x N fused (tag<<32 | fp32) words
};

#define DOT(wv, iv) ((wv).x*(iv).x + (wv).y*(iv).y + (wv).z*(iv).z + (wv).w*(iv).w)

__device__ __forceinline__ unsigned long long pack_iv(unsigned tag, float v) {
    return ((unsigned long long)tag << 32) | (unsigned long long)__float_as_uint(v);
}

__global__ __launch_bounds__(NTHR, 4)
void glif_persistent(Params p)
{
    cg::grid_group grid = cg::this_grid();
    __shared__ float ia_lds[2][N];        // 32 KB double buffer

    const int tid  = threadIdx.x;
    const int wg   = blockIdx.x;
    const int wave = tid >> 6;
    const int lane = tid & 63;
    const int row  = wg * ROWS_PER_WG + wave;   // wave-uniform neuron index

    // ---- wave-uniform params (scalarized by compiler)
    const float c_EL = p.E_L[row],  c_Cm = p.C_m[row], c_G   = p.G[row];
    const float c_RI = p.R_I[row],  c_fv = p.f_v[row], c_fI  = p.f_I[row];
    const float c_dts = p.dts[row], c_bs = p.b_s[row], c_av  = p.a_v[row];
    const float c_bv  = p.b_v[row], c_tinf = p.tinf[row];
    const float c_dV  = p.dV[row],  c_IA = p.I_A[row];

    float v  = p.v0[row], ts = p.ts0[row], tv = p.tv0[row];
    float ia = p.ia0[row];                // this wave OWNS I_add[row]

    // ---- this wave's w row in 16 named float4 regs (VGPR/AGPR resident)
    const float4* wr = (const float4*)(p.w + (size_t)row * N);
    const float4 w0  = wr[lane +   0], w1  = wr[lane +  64], w2  = wr[lane + 128],
                 w3  = wr[lane + 192], w4  = wr[lane + 256], w5  = wr[lane + 320],
                 w6  = wr[lane + 384], w7  = wr[lane + 448], w8  = wr[lane + 512],
                 w9  = wr[lane + 576], w10 = wr[lane + 640], w11 = wr[lane + 704],
                 w12 = wr[lane + 768], w13 = wr[lane + 832], w14 = wr[lane + 896],
                 w15 = wr[lane + 960];

    // ---- init: clear BOTH fused buffers (kills 0xAA poison AND cross-replay
    // stale tags), and fill LDS buffer 0 directly from ia0 (input, no x-WG dep)
    if (tid < 2 * N / NBLK)               // 32 words per WG
        __hip_atomic_store(&p.ia_tag[wg * (2 * N / NBLK) + tid], 0ull,
                           __ATOMIC_RELAXED, __HIP_MEMORY_SCOPE_AGENT);
    ((float4*)ia_lds[0])[tid] = ((const float4*)p.ia0)[tid];
    grid.sync();                          // once per launch; orders clears

    float x = p.x_in[row];                // preloaded x for t=0

    for (int t = 0; t < T; ++t) {
        const float4* lds4 = (const float4*)ia_lds[t & 1];

        // ---- matvec from register-resident w, LDS-broadcast I_add
        float a = 0.f;
        { float4 q = lds4[lane +   0]; a += DOT(w0 , q); }
        { float4 q = lds4[lane +  64]; a += DOT(w1 , q); }
        { float4 q = lds4[lane + 128]; a += DOT(w2 , q); }
        { float4 q = lds4[lane + 192]; a += DOT(w3 , q); }
        { float4 q = lds4[lane + 256]; a += DOT(w4 , q); }
        { float4 q = lds4[lane + 320]; a += DOT(w5 , q); }
        { float4 q = lds4[lane + 384]; a += DOT(w6 , q); }
        { float4 q = lds4[lane + 448]; a += DOT(w7 , q); }
        { float4 q = lds4[lane + 512]; a += DOT(w8 , q); }
        { float4 q = lds4[lane + 576]; a += DOT(w9 , q); }
        { float4 q = lds4[lane + 640]; a += DOT(w10, q); }
        { float4 q = lds4[lane + 704]; a += DOT(w11, q); }
        { float4 q = lds4[lane + 768]; a += DOT(w12, q); }
        { float4 q = lds4[lane + 832]; a += DOT(w13, q); }
        { float4 q = lds4[lane + 896]; a += DOT(w14, q); }
        { float4 q = lds4[lane + 960]; a += DOT(w15, q); }

        #pragma unroll
        for (int m = 32; m >= 1; m >>= 1)
            a += __shfl_xor(a, m, 64);

        // ---- neuron update, ia_new FIRST (it's the cross-WG critical path)
        float I      = x + a;
        float dv     = (I * c_RI - c_G * (v - c_EL)) / c_Cm;
        float v_next = v + dv;
        float thr    = ts + tv;
        float ssoft  = 1.f / (1.f + __expf(thr - v_next)); // sigmoid(v_next-thr)
        float ia_new = (1.f - c_fI) * ia + ssoft * c_IA;

        unsigned long long* dst64 = p.ia_tag + (size_t)((t + 1) & 1) * N;
        if (lane == 0)                    // single fused publish: data+tag
            __hip_atomic_store(&dst64[row], pack_iv((unsigned)(t + 2), ia_new),
                               __ATOMIC_RELAXED, __HIP_MEMORY_SCOPE_AGENT);

        bool  sp     = (v_next >= thr);
        float v_reset = c_EL + c_fv * (v - c_EL) - c_dV;
        float v_new  = sp ? v_reset : v_next;
        float ts_new = (1.f - c_bs) * ts + (sp ? c_dts : 0.f);
        float dtv    = c_av * (v_new - c_EL) - c_bv * (tv - c_tinf);
        float tv_new = tv + (sp ? 0.f : dtv);

        v = v_new; ts = ts_new; tv = tv_new; ia = ia_new;

        if (lane == 0) {
            p.out[(size_t)t * N + row] = v_new;                 // cached, ok
            p.out[(size_t)T * N + (size_t)t * N + row] = ssoft; // cached, ok
        }

        if (t + 1 < T) {
            // ---- prefetch next x (latency hides under the poll)
            x = p.x_in[(size_t)(t + 1) * N + row];

            // ---- poll NEXT step's fused words straight into the other LDS buf
            const unsigned long long* nb = dst64;   // buffer all WGs publish to
            const unsigned tg = (unsigned)(t + 2);
            const int b = 4 * tid;
            unsigned long long q0 = 0, q1 = 0, q2 = 0, q3 = 0;
            bool d0 = false, d1 = false, d2 = false, d3 = false;
            for (;;) {
                if (!d0) { q0 = __hip_atomic_load(nb + b + 0, __ATOMIC_RELAXED,
                               __HIP_MEMORY_SCOPE_AGENT); d0 = (unsigned)(q0 >> 32) == tg; }
                if (!d1) { q1 = __hip_atomic_load(nb + b + 1, __ATOMIC_RELAXED,
                               __HIP_MEMORY_SCOPE_AGENT); d1 = (unsigned)(q1 >> 32) == tg; }
                if (!d2) { q2 = __hip_atomic_load(nb + b + 2, __ATOMIC_RELAXED,
                               __HIP_MEMORY_SCOPE_AGENT); d2 = (unsigned)(q2 >> 32) == tg; }
                if (!d3) { q3 = __hip_atomic_load(nb + b + 3, __ATOMIC_RELAXED,
                               __HIP_MEMORY_SCOPE_AGENT); d3 = (unsigned)(q3 >> 32) == tg; }
                if (d0 & d1 & d2 & d3) break;
                __builtin_amdgcn_s_sleep(1);
            }
            float4 f;
            f.x = __uint_as_float((unsigned)q0);
            f.y = __uint_as_float((unsigned)q1);
            f.z = __uint_as_float((unsigned)q2);
            f.w = __uint_as_float((unsigned)q3);
            ((float4*)ia_lds[(t + 1) & 1])[tid] = f;
        }

        // one block barrier per step: publishes LDS buffer (t+1)&1 for the next
        // matvec, and orders this step's lds reads before next step's writes.
        __syncthreads();
    }
}

extern "C" void kernel_launch(void* const* d_in, const int* in_sizes, int n_in,
                              void* d_out, int out_size, void* d_ws, size_t ws_size,
                              hipStream_t stream)
{
    Params p;
    p.x_in = (const float*)d_in[0];
    p.w    = (const float*)d_in[1];
    p.E_L  = (const float*)d_in[2];
    p.C_m  = (const float*)d_in[3];
    p.G    = (const float*)d_in[4];
    p.R_I  = (const float*)d_in[5];
    p.f_v  = (const float*)d_in[6];
    p.f_I  = (const float*)d_in[7];
    p.dts  = (const float*)d_in[8];
    p.b_s  = (const float*)d_in[9];
    p.a_v  = (const float*)d_in[10];
    p.b_v  = (const float*)d_in[11];
    p.tinf = (const float*)d_in[12];
    p.dV   = (const float*)d_in[13];
    p.I_A  = (const float*)d_in[14];
    p.v0   = (const float*)d_in[15];
    p.ts0  = (const float*)d_in[16];
    p.tv0  = (const float*)d_in[17];
    p.ia0  = (const float*)d_in[18];
    p.out  = (float*)d_out;
    p.ia_tag = (unsigned long long*)d_ws;   // 2 * 4096 * 8 B = 64 KB

    void* args[] = { &p };
    hipLaunchCooperativeKernel((const void*)glif_persistent,
                               dim3(NBLK), dim3(NTHR), args, 0, stream);
}

// Round 8
// 6719.172 us; speedup vs baseline: 2.2010x; 2.2010x over previous
//
#include <hip/hip_runtime.h>
#include <hip/hip_cooperative_groups.h>

namespace cg = cooperative_groups;

constexpr int N    = 4096;
constexpr int T    = 2048;
constexpr int NBLK = 256;                 // one WG per CU
constexpr int NTHR = 512;                 // 8 waves
constexpr int ROWS_PER_WG   = 16;
constexpr int ROWS_PER_WAVE = 2;          // 8 waves x 2 rows

struct Params {
    const float *x_in, *w, *E_L, *C_m, *G, *R_I, *f_v, *f_I, *dts, *b_s,
                *a_v, *b_v, *tinf, *dV, *I_A, *v0, *ts0, *tv0, *ia0;
    float *out;          // [2, T, N]
    unsigned *flags;     // 256 packed u32 flags (1 KB) at d_ws
    float *ia_buf;       // double buffer 2*N floats at d_ws + 4 KB
};

#define DOT(wv, iv) ((wv).x*(iv).x + (wv).y*(iv).y + (wv).z*(iv).z + (wv).w*(iv).w)
#define AGLD(ptr) __hip_atomic_load(ptr, __ATOMIC_RELAXED, __HIP_MEMORY_SCOPE_AGENT)
#define AGST(ptr, val) __hip_atomic_store(ptr, val, __ATOMIC_RELAXED, __HIP_MEMORY_SCOPE_AGENT)

__global__ __launch_bounds__(NTHR, 2)
void glif_persistent(Params p)
{
    cg::grid_group grid = cg::this_grid();
    __shared__ float ia_lds[2][N];        // 32 KB double buffer

    const int tid  = threadIdx.x;
    const int wg   = blockIdx.x;
    const int wave = tid >> 6;
    const int lane = tid & 63;
    const int row0 = wg * ROWS_PER_WG + wave * ROWS_PER_WAVE;
    // lane 0 -> row0 (row A); every other lane -> row0+1 (row B).
    // Lanes >= 2 redundantly compute row B and never store. ALL in-bounds.
    const int prow = row0 + (lane != 0);

    // ---- per-lane params/state (meaningful for lane<2 only)
    const float c_EL = p.E_L[prow],  c_Cm = p.C_m[prow], c_G   = p.G[prow];
    const float c_RI = p.R_I[prow],  c_fv = p.f_v[prow], c_fI  = p.f_I[prow];
    const float c_dts = p.dts[prow], c_bs = p.b_s[prow], c_av  = p.a_v[prow];
    const float c_bv  = p.b_v[prow], c_tinf = p.tinf[prow];
    const float c_dV  = p.dV[prow],  c_IA = p.I_A[prow];
    float v  = p.v0[prow], ts = p.ts0[prow], tv = p.tv0[prow];
    float ia = p.ia0[prow];

    // ---- this wave's TWO w rows in 32 named float4 regs (128 VGPR)
    const float4* wrA = (const float4*)(p.w + (size_t)(row0 + 0) * N);
    const float4* wrB = (const float4*)(p.w + (size_t)(row0 + 1) * N);
    const float4 a0r = wrA[lane+0],   a1r = wrA[lane+64],  a2r = wrA[lane+128],
                 a3r = wrA[lane+192], a4r = wrA[lane+256], a5r = wrA[lane+320],
                 a6r = wrA[lane+384], a7r = wrA[lane+448], a8r = wrA[lane+512],
                 a9r = wrA[lane+576], aAr = wrA[lane+640], aBr = wrA[lane+704],
                 aCr = wrA[lane+768], aDr = wrA[lane+832], aEr = wrA[lane+896],
                 aFr = wrA[lane+960];
    const float4 b0r = wrB[lane+0],   b1r = wrB[lane+64],  b2r = wrB[lane+128],
                 b3r = wrB[lane+192], b4r = wrB[lane+256], b5r = wrB[lane+320],
                 b6r = wrB[lane+384], b7r = wrB[lane+448], b8r = wrB[lane+512],
                 b9r = wrB[lane+576], bAr = wrB[lane+640], bBr = wrB[lane+704],
                 bCr = wrB[lane+768], bDr = wrB[lane+832], bEr = wrB[lane+896],
                 bFr = wrB[lane+960];

    // ---- init: zero own flag (kills 0xAA poison + stale replay tags);
    // fill LDS buffer 0 straight from ia0 (input; no cross-WG dependency)
    if (tid == 0) AGST(&p.flags[wg], 0u);
    ((float4*)ia_lds[0])[tid]        = ((const float4*)p.ia0)[tid];
    ((float4*)ia_lds[0])[tid + NTHR] = ((const float4*)p.ia0)[tid + NTHR];
    grid.sync();                          // once per launch

    float x = p.x_in[prow];               // x for t=0 (lanes 0,1 meaningful)

    for (int t = 0; t < T; ++t) {
        const float4* lds4 = (const float4*)ia_lds[t & 1];

        // ---- matvec: 2 register-resident rows per wave, shared LDS reads
        float sA = 0.f, sB = 0.f;
        { float4 q = lds4[lane+  0]; sA += DOT(a0r,q); sB += DOT(b0r,q); }
        { float4 q = lds4[lane+ 64]; sA += DOT(a1r,q); sB += DOT(b1r,q); }
        { float4 q = lds4[lane+128]; sA += DOT(a2r,q); sB += DOT(b2r,q); }
        { float4 q = lds4[lane+192]; sA += DOT(a3r,q); sB += DOT(b3r,q); }
        { float4 q = lds4[lane+256]; sA += DOT(a4r,q); sB += DOT(b4r,q); }
        { float4 q = lds4[lane+320]; sA += DOT(a5r,q); sB += DOT(b5r,q); }
        { float4 q = lds4[lane+384]; sA += DOT(a6r,q); sB += DOT(b6r,q); }
        { float4 q = lds4[lane+448]; sA += DOT(a7r,q); sB += DOT(b7r,q); }
        { float4 q = lds4[lane+512]; sA += DOT(a8r,q); sB += DOT(b8r,q); }
        { float4 q = lds4[lane+576]; sA += DOT(a9r,q); sB += DOT(b9r,q); }
        { float4 q = lds4[lane+640]; sA += DOT(aAr,q); sB += DOT(bAr,q); }
        { float4 q = lds4[lane+704]; sA += DOT(aBr,q); sB += DOT(bBr,q); }
        { float4 q = lds4[lane+768]; sA += DOT(aCr,q); sB += DOT(bCr,q); }
        { float4 q = lds4[lane+832]; sA += DOT(aDr,q); sB += DOT(bDr,q); }
        { float4 q = lds4[lane+896]; sA += DOT(aEr,q); sB += DOT(bEr,q); }
        { float4 q = lds4[lane+960]; sA += DOT(aFr,q); sB += DOT(bFr,q); }

        #pragma unroll
        for (int m = 32; m >= 1; m >>= 1) {
            sA += __shfl_xor(sA, m, 64);
            sB += __shfl_xor(sB, m, 64);
        }

        // ---- update core (lane0 = row A, all other lanes = row B; only
        // lanes 0,1 ever store results)
        float a      = (lane == 0) ? sA : sB;
        float I      = x + a;
        float dv     = (I * c_RI - c_G * (v - c_EL)) / c_Cm;
        float v_next = v + dv;
        float thr    = ts + tv;
        float ssoft  = 1.f / (1.f + __expf(thr - v_next)); // sigmoid(v_next-thr)
        float ia_new = (1.f - c_fI) * ia + ssoft * c_IA;

        // ---- publish I_add FIRST: only these 2 stores gate the flag
        float* dst = p.ia_buf + (size_t)((t + 1) & 1) * N;
        if (lane < 2) AGST(&dst[prow], ia_new);

        __syncthreads();                  // #1: vmcnt(0) -> all ia stores at L3

        const bool notlast = (t + 1 < T);
        const unsigned tgt = (unsigned)(t + 1);

        if (wave == 0 && lane == 0 && notlast)
            AGST(&p.flags[wg], tgt);      // tag goes out immediately after #1

        // ---- bookkeeping + out stores + x prefetch: in the poll shadow
        {
            bool  sp      = (v_next >= thr);
            float v_reset = c_EL + c_fv * (v - c_EL) - c_dV;
            float v_new   = sp ? v_reset : v_next;
            float ts_new  = (1.f - c_bs) * ts + (sp ? c_dts : 0.f);
            float dtv     = c_av * (v_new - c_EL) - c_bv * (tv - c_tinf);
            float tv_new  = tv + (sp ? 0.f : dtv);
            v = v_new; ts = ts_new; tv = tv_new; ia = ia_new;
            if (lane < 2) {
                p.out[(size_t)t * N + prow] = v_new;
                p.out[(size_t)T * N + (size_t)t * N + prow] = ssoft;
                if (notlast) x = p.x_in[(size_t)(t + 1) * N + prow];
            }
        }

        if (notlast) {
            if (wave == 0) {
                // ---- poll 256 packed flags (1 KB): 2 u64 per lane,
                // sticky >= on each u32 half (monotonic tags -> no livelock)
                const unsigned long long* f64 =
                    (const unsigned long long*)p.flags;
                bool d0 = false, d1 = false;
                for (;;) {
                    if (!d0) {
                        unsigned long long q = AGLD(&f64[lane]);
                        d0 = ((unsigned)q >= tgt) & ((unsigned)(q >> 32) >= tgt);
                    }
                    if (!d1) {
                        unsigned long long q = AGLD(&f64[lane + 64]);
                        d1 = ((unsigned)q >= tgt) & ((unsigned)(q >> 32) >= tgt);
                    }
                    if (__all(d0 && d1)) break;
                    __builtin_amdgcn_s_sleep(1);
                }
            }
            __syncthreads();              // #2: wave0 confirms everyone published

            // ---- bulk read fresh I_add (L3-direct) into the other LDS buffer
            const unsigned long long* src64 =
                (const unsigned long long*)(p.ia_buf + (size_t)((t + 1) & 1) * N);
            unsigned long long q0 = AGLD(&src64[tid            ]);
            unsigned long long q1 = AGLD(&src64[tid + NTHR     ]);
            unsigned long long q2 = AGLD(&src64[tid + 2 * NTHR ]);
            unsigned long long q3 = AGLD(&src64[tid + 3 * NTHR ]);
            unsigned long long* l64 = (unsigned long long*)ia_lds[(t + 1) & 1];
            l64[tid           ] = q0;
            l64[tid + NTHR    ] = q1;
            l64[tid + 2 * NTHR] = q2;
            l64[tid + 3 * NTHR] = q3;

            __syncthreads();              // #3: LDS buffer ready for next matvec
        }
    }
}

extern "C" void kernel_launch(void* const* d_in, const int* in_sizes, int n_in,
                              void* d_out, int out_size, void* d_ws, size_t ws_size,
                              hipStream_t stream)
{
    Params p;
    p.x_in = (const float*)d_in[0];
    p.w    = (const float*)d_in[1];
    p.E_L  = (const float*)d_in[2];
    p.C_m  = (const float*)d_in[3];
    p.G    = (const float*)d_in[4];
    p.R_I  = (const float*)d_in[5];
    p.f_v  = (const float*)d_in[6];
    p.f_I  = (const float*)d_in[7];
    p.dts  = (const float*)d_in[8];
    p.b_s  = (const float*)d_in[9];
    p.a_v  = (const float*)d_in[10];
    p.b_v  = (const float*)d_in[11];
    p.tinf = (const float*)d_in[12];
    p.dV   = (const float*)d_in[13];
    p.I_A  = (const float*)d_in[14];
    p.v0   = (const float*)d_in[15];
    p.ts0  = (const float*)d_in[16];
    p.tv0  = (const float*)d_in[17];
    p.ia0  = (const float*)d_in[18];
    p.out  = (float*)d_out;
    p.flags  = (unsigned*)d_ws;                      // 256 * 4 B = 1 KB
    p.ia_buf = (float*)((char*)d_ws + 4096);         // 2*N*4 = 32 KB

    void* args[] = { &p };
    hipLaunchCooperativeKernel((const void*)glif_persistent,
                               dim3(NBLK), dim3(NTHR), args, 0, stream);
}